// Round 1
// baseline (4405.787 us; speedup 1.0000x reference)
//
#include <hip/hip_runtime.h>
#include <hip/hip_bf16.h>
#include <math.h>

#define N_NODES 50000
#define N_EDGES 800000
#define EMB 128
#define LH 256
#define NSENT 2048
#define MAXLEN 32

// ---------------- CSR build (per launch; ws is re-poisoned every call) ----------------

__global__ void k_hist(const int* __restrict__ dst, int* __restrict__ cnt) {
    int i = blockIdx.x * 256 + threadIdx.x;
    if (i < N_EDGES) atomicAdd(&cnt[dst[i]], 1);
}

// single-block exclusive scan over 50000 ints, wave-shuffle based (few barriers)
__global__ void k_scan(const int* __restrict__ cnt, int* __restrict__ row_ptr) {
    __shared__ int wsum[16];
    __shared__ int chunk_tot;
    __shared__ int carry_s;
    int t = threadIdx.x, lane = t & 63, wid = t >> 6;
    if (t == 0) carry_s = 0;
    __syncthreads();
    for (int base = 0; base < N_NODES; base += 1024) {
        int i = base + t;
        int v = (i < N_NODES) ? cnt[i] : 0;
        int x = v;
        #pragma unroll
        for (int off = 1; off < 64; off <<= 1) {
            int y = __shfl_up(x, off);
            if (lane >= off) x += y;
        }
        if (lane == 63) wsum[wid] = x;
        __syncthreads();
        if (wid == 0) {
            int ws = (lane < 16) ? wsum[lane] : 0;
            int xs = ws;
            #pragma unroll
            for (int off = 1; off < 16; off <<= 1) {
                int y = __shfl_up(xs, off);
                if (lane >= off) xs += y;
            }
            if (lane < 16) wsum[lane] = xs - ws;   // exclusive per-wave offset
            if (lane == 15) chunk_tot = xs;        // inclusive total of chunk
        }
        __syncthreads();
        if (i < N_NODES) row_ptr[i] = carry_s + wsum[wid] + x - v;
        __syncthreads();
        if (t == 0) carry_s += chunk_tot;
        __syncthreads();
    }
    if (t == 0) row_ptr[N_NODES] = carry_s;
}

__global__ void k_scatter(const int* __restrict__ src, const int* __restrict__ dst,
                          const int* __restrict__ row_ptr, int* __restrict__ cnt,
                          int* __restrict__ edge_src) {
    int i = blockIdx.x * 256 + threadIdx.x;
    if (i < N_EDGES) {
        int d = dst[i];
        int pos = row_ptr[d] + atomicAdd(&cnt[d], 1);
        edge_src[pos] = src[i];
    }
}

// ---------------- aggregation: wave per node, float2 per lane ----------------

__global__ void k_aggregate(const float* __restrict__ feat,
                            const int* __restrict__ row_ptr,
                            const int* __restrict__ edge_src,
                            float* __restrict__ out) {
    int w = (blockIdx.x * 256 + threadIdx.x) >> 6;
    int lane = threadIdx.x & 63;
    if (w >= N_NODES) return;
    int beg = row_ptr[w], end = row_ptr[w + 1];
    float2 acc = make_float2(0.f, 0.f);
    int e = beg;
    for (; e + 2 <= end; e += 2) {
        int s0 = edge_src[e], s1 = edge_src[e + 1];
        float2 v0 = *(const float2*)(feat + (size_t)s0 * EMB + 2 * lane);
        float2 v1 = *(const float2*)(feat + (size_t)s1 * EMB + 2 * lane);
        acc.x += v0.x + v1.x;
        acc.y += v0.y + v1.y;
    }
    if (e < end) {
        int s0 = edge_src[e];
        float2 v0 = *(const float2*)(feat + (size_t)s0 * EMB + 2 * lane);
        acc.x += v0.x;
        acc.y += v0.y;
    }
    *(float2*)(out + (size_t)w * EMB + 2 * lane) = acc;
}

// ---------------- GCN linear: out[M][128] = act(A[M][128] @ W.T + b) ----------------
// W row-major [j][k]. Block = 128 threads (thread = output col j), 16 rows per block.
// A-row reads are wave-uniform -> compiler emits s_load_dwordx4 (SMEM pipe, frees VALU).

__global__ void k_gcn_gemm(const float* __restrict__ A, const float* __restrict__ W,
                           const float* __restrict__ bias, float* __restrict__ out,
                           int do_tanh) {
    int j = threadIdx.x;            // 0..127
    int rbase = blockIdx.x * 16;
    float b = bias[j];
    float acc[16];
    #pragma unroll
    for (int r = 0; r < 16; r++) acc[r] = b;
    const float4* Wj = (const float4*)(W + (size_t)j * EMB);
    #pragma unroll 2
    for (int k4 = 0; k4 < EMB / 4; k4++) {
        float4 w = Wj[k4];
        #pragma unroll
        for (int r = 0; r < 16; r++) {
            float4 a = *(const float4*)(A + (size_t)(rbase + r) * EMB + k4 * 4);
            acc[r] += a.x * w.x + a.y * w.y + a.z * w.z + a.w * w.w;
        }
    }
    #pragma unroll
    for (int r = 0; r < 16; r++) {
        float v = acc[r];
        if (do_tanh) v = tanhf(v);
        out[(size_t)(rbase + r) * EMB + j] = v;
    }
}

// ---------------- LSTM step: gates GEMM (K=384, fused gather) + state update ----------------
// grid = (NSENT/32, 4); block 256. thread: g = tid>>6 (gate), u_l = tid&63 (unit within
// the 64-unit chunk). Each thread accumulates its gate/unit column for 32 sentences.
// A (shared operand) is read via wave-uniform scalar loads; B (weight row) is per-thread
// and register-cached across the 32-sentence strip.

__global__ void __launch_bounds__(256)
k_lstm_step(const float* __restrict__ hn,      // [N_NODES][128]
            const float* __restrict__ h_in,    // [NSENT][256]
            const float* __restrict__ Wi,      // [1024][128]
            const float* __restrict__ Wh,      // [1024][256]
            const float* __restrict__ bi, const float* __restrict__ bh,
            const int* __restrict__ sidx,      // [NSENT][MAXLEN]
            const int* __restrict__ lengths,   // [NSENT]
            float* __restrict__ c_st,          // [NSENT][256]
            float* __restrict__ h_out,         // [NSENT][256]
            float* __restrict__ h_last,        // [NSENT][256]
            int t) {
    __shared__ int nid_s[32];
    __shared__ float gl[256 * 33];             // [o_local 256][33] gate staging, pad 33
    int tid = threadIdx.x;
    int g = tid >> 6, u_l = tid & 63;
    int schunk = blockIdx.x, ublk = blockIdx.y;
    int u = ublk * 64 + u_l;
    int R = g * 256 + u;                       // row in Wi/Wh/bias (gate-major, torch order)
    if (tid < 32) nid_s[tid] = sidx[(schunk * 32 + tid) * MAXLEN + t];
    __syncthreads();

    float acc[32];
    {
        float bsum = bi[R] + bh[R];
        #pragma unroll
        for (int s = 0; s < 32; s++) acc[s] = bsum;
    }

    // Phase X: gates += x_t @ Wi.T ; x_t[s] = hn[nid[s]]
    const float4* Bx = (const float4*)(Wi + (size_t)R * 128);
    for (int k4 = 0; k4 < 32; k4++) {
        float4 b4 = Bx[k4];
        #pragma unroll
        for (int s = 0; s < 32; s++) {
            int nid = __builtin_amdgcn_readfirstlane(nid_s[s]);   // uniform -> s_load
            float4 a = *(const float4*)(hn + (size_t)nid * 128 + k4 * 4);
            acc[s] += a.x * b4.x + a.y * b4.y + a.z * b4.z + a.w * b4.w;
        }
    }
    // Phase H: gates += h_prev @ Wh.T
    const float4* Bh4 = (const float4*)(Wh + (size_t)R * 256);
    const float* hrow = h_in + (size_t)schunk * 32 * 256;
    for (int k4 = 0; k4 < 64; k4++) {
        float4 b4 = Bh4[k4];
        #pragma unroll
        for (int s = 0; s < 32; s++) {
            float4 a = *(const float4*)(hrow + (size_t)s * 256 + k4 * 4);  // uniform -> s_load
            acc[s] += a.x * b4.x + a.y * b4.y + a.z * b4.z + a.w * b4.w;
        }
    }

    // stage gates: gl[(g*64+u_l)][s]  (stride 33 -> conflict-free b32)
    {
        float* dstp = gl + (size_t)(g * 64 + u_l) * 33;
        #pragma unroll
        for (int s = 0; s < 32; s++) dstp[s] = acc[s];
    }
    __syncthreads();

    // update: thread handles 8 sentences x 1 unit (all 4 gates read from LDS)
    {
        int u2 = ublk * 64 + (tid & 63);
        int sq = tid >> 6;
        #pragma unroll
        for (int ss = 0; ss < 8; ss++) {
            int s = sq * 8 + ss;
            int ul2 = tid & 63;
            float gi = gl[(0 * 64 + ul2) * 33 + s];
            float gf = gl[(1 * 64 + ul2) * 33 + s];
            float gg = gl[(2 * 64 + ul2) * 33 + s];
            float go = gl[(3 * 64 + ul2) * 33 + s];
            int sg = schunk * 32 + s;
            float i_ = 1.f / (1.f + expf(-gi));
            float f_ = 1.f / (1.f + expf(-gf));
            float g_ = tanhf(gg);
            float o_ = 1.f / (1.f + expf(-go));
            size_t off = (size_t)sg * 256 + u2;
            float c = f_ * c_st[off] + i_ * g_;
            float h = o_ * tanhf(c);
            c_st[off] = c;
            h_out[off] = h;
            if (lengths[sg] - 1 == t) h_last[off] = h;
        }
    }
}

// ---------------- classifier: relu -> linear(256->128) -> relu -> linear(128->1) ----------------
// wave per sentence; 4 waves per block.

__global__ void k_classifier(const float* __restrict__ h_last,
                             const float* __restrict__ Wc1, const float* __restrict__ bc1,
                             const float* __restrict__ Wc2, const float* __restrict__ bc2,
                             float* __restrict__ out) {
    int lane = threadIdx.x & 63;
    int wslot = threadIdx.x >> 6;
    int s = blockIdx.x * 4 + wslot;
    __shared__ float e_sh[4][256];
    const float* hr = h_last + (size_t)s * 256;
    #pragma unroll
    for (int i = 0; i < 4; i++) {
        float v = hr[lane + 64 * i];
        e_sh[wslot][lane + 64 * i] = fmaxf(v, 0.f);
    }
    __syncthreads();
    float zpart = 0.f;
    #pragma unroll
    for (int jj = 0; jj < 2; jj++) {
        int j = lane + 64 * jj;
        float a = bc1[j];
        const float4* wr = (const float4*)(Wc1 + (size_t)j * 256);
        #pragma unroll 8
        for (int k4 = 0; k4 < 64; k4++) {
            float4 w = wr[k4];
            float4 e = *(const float4*)&e_sh[wslot][k4 * 4];
            a += w.x * e.x + w.y * e.y + w.z * e.z + w.w * e.w;
        }
        a = fmaxf(a, 0.f);
        zpart += a * Wc2[j];
    }
    #pragma unroll
    for (int off = 32; off > 0; off >>= 1) zpart += __shfl_down(zpart, off);
    if (lane == 0) out[s] = zpart + bc2[0];
}

// ---------------- launcher ----------------

extern "C" void kernel_launch(void* const* d_in, const int* in_sizes, int n_in,
                              void* d_out, int out_size, void* d_ws, size_t ws_size,
                              hipStream_t stream) {
    const float* inputs = (const float*)d_in[0];
    const float* W1  = (const float*)d_in[1];
    const float* b1  = (const float*)d_in[2];
    const float* W2  = (const float*)d_in[3];
    const float* b2  = (const float*)d_in[4];
    const float* Wi  = (const float*)d_in[5];
    const float* Wh  = (const float*)d_in[6];
    const float* bi  = (const float*)d_in[7];
    const float* bh  = (const float*)d_in[8];
    const float* Wc1 = (const float*)d_in[9];
    const float* bc1 = (const float*)d_in[10];
    const float* Wc2 = (const float*)d_in[11];
    const float* bc2 = (const float*)d_in[12];
    const int* src      = (const int*)d_in[13];
    const int* dst      = (const int*)d_in[14];
    const int* sidx     = (const int*)d_in[15];
    const int* lengths  = (const int*)d_in[16];
    float* out = (float*)d_out;

    char* ws = (char*)d_ws;
    size_t off = 0;
    auto alloc = [&](size_t bytes) -> void* {
        void* p = ws + off;
        off = (off + bytes + 255) & ~(size_t)255;
        return p;
    };
    float* agg      = (float*)alloc(sizeof(float) * (size_t)N_NODES * EMB);
    float* hbuf     = (float*)alloc(sizeof(float) * (size_t)N_NODES * EMB);
    int*   row_ptr  = (int*)alloc(sizeof(int) * (N_NODES + 1));
    int*   cnt      = (int*)alloc(sizeof(int) * N_NODES);
    int*   edge_src = (int*)alloc(sizeof(int) * N_EDGES);
    float* hA       = (float*)alloc(sizeof(float) * NSENT * LH);
    float* hB       = (float*)alloc(sizeof(float) * NSENT * LH);
    float* cst      = (float*)alloc(sizeof(float) * NSENT * LH);
    float* hlast    = (float*)alloc(sizeof(float) * NSENT * LH);

    // CSR build
    hipMemsetAsync(cnt, 0, sizeof(int) * N_NODES, stream);
    k_hist<<<(N_EDGES + 255) / 256, 256, 0, stream>>>(dst, cnt);
    k_scan<<<1, 1024, 0, stream>>>(cnt, row_ptr);
    hipMemsetAsync(cnt, 0, sizeof(int) * N_NODES, stream);
    k_scatter<<<(N_EDGES + 255) / 256, 256, 0, stream>>>(src, dst, row_ptr, cnt, edge_src);

    // GCN
    k_aggregate<<<(N_NODES * 64) / 256, 256, 0, stream>>>(inputs, row_ptr, edge_src, agg);
    k_gcn_gemm<<<N_NODES / 16, 128, 0, stream>>>(agg, W1, b1, hbuf, 1);
    k_aggregate<<<(N_NODES * 64) / 256, 256, 0, stream>>>(hbuf, row_ptr, edge_src, agg);
    k_gcn_gemm<<<N_NODES / 16, 128, 0, stream>>>(agg, W2, b2, hbuf, 0);

    // LSTM
    hipMemsetAsync(hA, 0, sizeof(float) * NSENT * LH, stream);
    hipMemsetAsync(cst, 0, sizeof(float) * NSENT * LH, stream);
    for (int t = 0; t < MAXLEN; t++) {
        float* hi = (t & 1) ? hB : hA;
        float* ho = (t & 1) ? hA : hB;
        k_lstm_step<<<dim3(NSENT / 32, 4), 256, 0, stream>>>(
            hbuf, hi, Wi, Wh, bi, bh, sidx, lengths, cst, ho, hlast, t);
    }

    // classifier
    k_classifier<<<NSENT / 4, 256, 0, stream>>>(hlast, Wc1, bc1, Wc2, bc2, out);
}

// Round 2
// 943.677 us; speedup vs baseline: 4.6687x; 4.6687x over previous
//
#include <hip/hip_runtime.h>
#include <hip/hip_bf16.h>
#include <math.h>

#define N_NODES 50000
#define N_EDGES 800000
#define EMB 128
#define LH 256
#define NSENT 2048
#define MAXLEN 32

typedef __attribute__((ext_vector_type(8))) short short8;
typedef __attribute__((ext_vector_type(4))) float f32x4;

// ---------------- CSR build (per launch; ws is re-poisoned every call) ----------------

__global__ void k_hist(const int* __restrict__ dst, int* __restrict__ cnt) {
    int i = blockIdx.x * 256 + threadIdx.x;
    if (i < N_EDGES) atomicAdd(&cnt[dst[i]], 1);
}

__global__ void k_scan(const int* __restrict__ cnt, int* __restrict__ row_ptr) {
    __shared__ int wsum[16];
    __shared__ int chunk_tot;
    __shared__ int carry_s;
    int t = threadIdx.x, lane = t & 63, wid = t >> 6;
    if (t == 0) carry_s = 0;
    __syncthreads();
    for (int base = 0; base < N_NODES; base += 1024) {
        int i = base + t;
        int v = (i < N_NODES) ? cnt[i] : 0;
        int x = v;
        #pragma unroll
        for (int off = 1; off < 64; off <<= 1) {
            int y = __shfl_up(x, off);
            if (lane >= off) x += y;
        }
        if (lane == 63) wsum[wid] = x;
        __syncthreads();
        if (wid == 0) {
            int ws = (lane < 16) ? wsum[lane] : 0;
            int xs = ws;
            #pragma unroll
            for (int off = 1; off < 16; off <<= 1) {
                int y = __shfl_up(xs, off);
                if (lane >= off) xs += y;
            }
            if (lane < 16) wsum[lane] = xs - ws;   // exclusive per-wave offset
            if (lane == 15) chunk_tot = xs;        // inclusive total of chunk
        }
        __syncthreads();
        if (i < N_NODES) row_ptr[i] = carry_s + wsum[wid] + x - v;
        __syncthreads();
        if (t == 0) carry_s += chunk_tot;
        __syncthreads();
    }
    if (t == 0) row_ptr[N_NODES] = carry_s;
}

__global__ void k_scatter(const int* __restrict__ src, const int* __restrict__ dst,
                          const int* __restrict__ row_ptr, int* __restrict__ cnt,
                          int* __restrict__ edge_src) {
    int i = blockIdx.x * 256 + threadIdx.x;
    if (i < N_EDGES) {
        int d = dst[i];
        int pos = row_ptr[d] + atomicAdd(&cnt[d], 1);
        edge_src[pos] = src[i];
    }
}

// ---------------- aggregation: wave per node, float2 per lane ----------------

__global__ void k_aggregate(const float* __restrict__ feat,
                            const int* __restrict__ row_ptr,
                            const int* __restrict__ edge_src,
                            float* __restrict__ out) {
    int w = (blockIdx.x * 256 + threadIdx.x) >> 6;
    int lane = threadIdx.x & 63;
    if (w >= N_NODES) return;
    int beg = row_ptr[w], end = row_ptr[w + 1];
    float2 acc = make_float2(0.f, 0.f);
    int e = beg;
    for (; e + 2 <= end; e += 2) {
        int s0 = edge_src[e], s1 = edge_src[e + 1];
        float2 v0 = *(const float2*)(feat + (size_t)s0 * EMB + 2 * lane);
        float2 v1 = *(const float2*)(feat + (size_t)s1 * EMB + 2 * lane);
        acc.x += v0.x + v1.x;
        acc.y += v0.y + v1.y;
    }
    if (e < end) {
        int s0 = edge_src[e];
        float2 v0 = *(const float2*)(feat + (size_t)s0 * EMB + 2 * lane);
        acc.x += v0.x;
        acc.y += v0.y;
    }
    *(float2*)(out + (size_t)w * EMB + 2 * lane) = acc;
}

// ---------------- GCN linear: out[M][128] = act(A[M][128] @ W.T + b) ----------------

__global__ void k_gcn_gemm(const float* __restrict__ A, const float* __restrict__ W,
                           const float* __restrict__ bias, float* __restrict__ out,
                           int do_tanh) {
    int j = threadIdx.x;            // 0..127
    int rbase = blockIdx.x * 16;
    float b = bias[j];
    float acc[16];
    #pragma unroll
    for (int r = 0; r < 16; r++) acc[r] = b;
    const float4* Wj = (const float4*)(W + (size_t)j * EMB);
    #pragma unroll 2
    for (int k4 = 0; k4 < EMB / 4; k4++) {
        float4 w = Wj[k4];
        #pragma unroll
        for (int r = 0; r < 16; r++) {
            float4 a = *(const float4*)(A + (size_t)(rbase + r) * EMB + k4 * 4);
            acc[r] += a.x * w.x + a.y * w.y + a.z * w.z + a.w * w.w;
        }
    }
    #pragma unroll
    for (int r = 0; r < 16; r++) {
        float v = acc[r];
        if (do_tanh) v = tanhf(v);
        out[(size_t)(rbase + r) * EMB + j] = v;
    }
}

// same, but bf16 output (layer 2 feeds the bf16 MFMA LSTM)
__global__ void k_gcn_gemm_bf(const float* __restrict__ A, const float* __restrict__ W,
                              const float* __restrict__ bias, __hip_bfloat16* __restrict__ out) {
    int j = threadIdx.x;
    int rbase = blockIdx.x * 16;
    float b = bias[j];
    float acc[16];
    #pragma unroll
    for (int r = 0; r < 16; r++) acc[r] = b;
    const float4* Wj = (const float4*)(W + (size_t)j * EMB);
    #pragma unroll 2
    for (int k4 = 0; k4 < EMB / 4; k4++) {
        float4 w = Wj[k4];
        #pragma unroll
        for (int r = 0; r < 16; r++) {
            float4 a = *(const float4*)(A + (size_t)(rbase + r) * EMB + k4 * 4);
            acc[r] += a.x * w.x + a.y * w.y + a.z * w.z + a.w * w.w;
        }
    }
    #pragma unroll
    for (int r = 0; r < 16; r++)
        out[(size_t)(rbase + r) * EMB + j] = __float2bfloat16(acc[r]);
}

// ---------------- prep: Wcat[1024][384] = bf16(Wi||Wh), bsum = bi+bh ----------------

__global__ void k_prep(const float* __restrict__ Wi, const float* __restrict__ Wh,
                       const float* __restrict__ bi, const float* __restrict__ bh,
                       __hip_bfloat16* __restrict__ Wcat, float* __restrict__ bsum) {
    int idx = blockIdx.x * 256 + threadIdx.x;
    if (idx < 1024 * 384) {
        int r = idx / 384, k = idx - r * 384;
        float v = (k < 128) ? Wi[r * 128 + k] : Wh[r * 256 + (k - 128)];
        Wcat[idx] = __float2bfloat16(v);
    } else if (idx < 1024 * 384 + 1024) {
        int r = idx - 1024 * 384;
        bsum[r] = bi[r] + bh[r];
    }
}

// ---------------- LSTM step via MFMA bf16 ----------------
// grid (NSENT/32, 4), block 256 (4 waves). Block: 32 sentences x 64 units (all 4 gates).
// Wave w: units qy*64 + w*16 + [0,16); n-tiles = rows {g*256+u} for g=0..3 -> for a
// given (sentence m, unit u) all four gates land in the SAME lane (different acc regs):
// pointwise update is per-lane register math, no LDS staging.
// Fragment convention (m97 gemm_bt, verified): A and W row-major, lane&15 = free-dim
// index, k = quad*8+j; D[row = quad*4+reg (A dim)][col = lane&15 (B dim)].

__global__ void __launch_bounds__(256)
k_lstm_mfma(const __hip_bfloat16* __restrict__ hn_bf,   // [N_NODES][128]
            const __hip_bfloat16* __restrict__ h_in,    // [NSENT][256] bf16
            const __hip_bfloat16* __restrict__ Wcat,    // [1024][384] bf16
            const float* __restrict__ bsum,             // [1024]
            const int* __restrict__ sidx,               // [NSENT][MAXLEN]
            const int* __restrict__ lengths,            // [NSENT]
            float* __restrict__ c_st,                   // [NSENT][256] fp32
            __hip_bfloat16* __restrict__ h_out,         // [NSENT][256] bf16
            float* __restrict__ h_last,                 // [NSENT][256] fp32
            int t) {
    __shared__ int nid_s[32];
    __shared__ int len_s[32];
    int tid = threadIdx.x;
    int w = tid >> 6, lane = tid & 63;
    int l16 = lane & 15, quad = lane >> 4;
    int schunk = blockIdx.x;
    int qy = blockIdx.y;
    if (tid < 32) nid_s[tid] = sidx[(schunk * 32 + tid) * MAXLEN + t];
    else if (tid < 64) len_s[tid - 32] = lengths[schunk * 32 + (tid - 32)];
    __syncthreads();

    const short* Wp = (const short*)Wcat;
    const short* Bb[4];
    #pragma unroll
    for (int g = 0; g < 4; g++) {
        int row = g * 256 + qy * 64 + w * 16 + l16;
        Bb[g] = Wp + (size_t)row * 384 + quad * 8;
    }
    int nid0 = nid_s[l16], nid1 = nid_s[16 + l16];
    const short* hnp = (const short*)hn_bf;
    const short* Ax0 = hnp + (size_t)nid0 * 128 + quad * 8;
    const short* Ax1 = hnp + (size_t)nid1 * 128 + quad * 8;
    const short* hp = (const short*)h_in;
    const short* Ah0 = hp + (size_t)(schunk * 32 + l16) * 256 + quad * 8;
    const short* Ah1 = hp + (size_t)(schunk * 32 + 16 + l16) * 256 + quad * 8;

    f32x4 acc[2][4] = {};   // [m-tile][gate]

    // X phase: gates += x_t @ Wi.T   (K = 128, 4 k-steps)
    #pragma unroll
    for (int ks = 0; ks < 4; ks++) {
        short8 a0 = *(const short8*)(Ax0 + ks * 32);
        short8 a1 = *(const short8*)(Ax1 + ks * 32);
        #pragma unroll
        for (int g = 0; g < 4; g++) {
            short8 b = *(const short8*)(Bb[g] + ks * 32);
            acc[0][g] = __builtin_amdgcn_mfma_f32_16x16x32_bf16(a0, b, acc[0][g], 0, 0, 0);
            acc[1][g] = __builtin_amdgcn_mfma_f32_16x16x32_bf16(a1, b, acc[1][g], 0, 0, 0);
        }
    }
    // H phase: gates += h_prev @ Wh.T   (K = 256, 8 k-steps)
    #pragma unroll 4
    for (int ks = 0; ks < 8; ks++) {
        short8 a0 = *(const short8*)(Ah0 + ks * 32);
        short8 a1 = *(const short8*)(Ah1 + ks * 32);
        #pragma unroll
        for (int g = 0; g < 4; g++) {
            short8 b = *(const short8*)(Bb[g] + 128 + ks * 32);
            acc[0][g] = __builtin_amdgcn_mfma_f32_16x16x32_bf16(a0, b, acc[0][g], 0, 0, 0);
            acc[1][g] = __builtin_amdgcn_mfma_f32_16x16x32_bf16(a1, b, acc[1][g], 0, 0, 0);
        }
    }

    // epilogue: per-lane LSTM pointwise update
    int u = qy * 64 + w * 16 + l16;
    float bs[4];
    #pragma unroll
    for (int g = 0; g < 4; g++) bs[g] = bsum[g * 256 + u];

    #pragma unroll
    for (int mt = 0; mt < 2; mt++) {
        #pragma unroll
        for (int r = 0; r < 4; r++) {
            int mloc = mt * 16 + quad * 4 + r;
            int m = schunk * 32 + mloc;
            float gi = acc[mt][0][r] + bs[0];
            float gf = acc[mt][1][r] + bs[1];
            float gg = acc[mt][2][r] + bs[2];
            float go = acc[mt][3][r] + bs[3];
            float i_ = 1.f / (1.f + expf(-gi));
            float f_ = 1.f / (1.f + expf(-gf));
            float g_ = tanhf(gg);
            float o_ = 1.f / (1.f + expf(-go));
            size_t off = (size_t)m * 256 + u;
            float c = f_ * c_st[off] + i_ * g_;
            c_st[off] = c;
            float h = o_ * tanhf(c);
            h_out[off] = __float2bfloat16(h);
            if (len_s[mloc] - 1 == t) h_last[off] = h;
        }
    }
}

// ---------------- classifier ----------------

__global__ void k_classifier(const float* __restrict__ h_last,
                             const float* __restrict__ Wc1, const float* __restrict__ bc1,
                             const float* __restrict__ Wc2, const float* __restrict__ bc2,
                             float* __restrict__ out) {
    int lane = threadIdx.x & 63;
    int wslot = threadIdx.x >> 6;
    int s = blockIdx.x * 4 + wslot;
    __shared__ float e_sh[4][256];
    const float* hr = h_last + (size_t)s * 256;
    #pragma unroll
    for (int i = 0; i < 4; i++) {
        float v = hr[lane + 64 * i];
        e_sh[wslot][lane + 64 * i] = fmaxf(v, 0.f);
    }
    __syncthreads();
    float zpart = 0.f;
    #pragma unroll
    for (int jj = 0; jj < 2; jj++) {
        int j = lane + 64 * jj;
        float a = bc1[j];
        const float4* wr = (const float4*)(Wc1 + (size_t)j * 256);
        #pragma unroll 8
        for (int k4 = 0; k4 < 64; k4++) {
            float4 wv = wr[k4];
            float4 e = *(const float4*)&e_sh[wslot][k4 * 4];
            a += wv.x * e.x + wv.y * e.y + wv.z * e.z + wv.w * e.w;
        }
        a = fmaxf(a, 0.f);
        zpart += a * Wc2[j];
    }
    #pragma unroll
    for (int off = 32; off > 0; off >>= 1) zpart += __shfl_down(zpart, off);
    if (lane == 0) out[s] = zpart + bc2[0];
}

// ---------------- launcher ----------------

extern "C" void kernel_launch(void* const* d_in, const int* in_sizes, int n_in,
                              void* d_out, int out_size, void* d_ws, size_t ws_size,
                              hipStream_t stream) {
    const float* inputs = (const float*)d_in[0];
    const float* W1  = (const float*)d_in[1];
    const float* b1  = (const float*)d_in[2];
    const float* W2  = (const float*)d_in[3];
    const float* b2  = (const float*)d_in[4];
    const float* Wi  = (const float*)d_in[5];
    const float* Wh  = (const float*)d_in[6];
    const float* bi  = (const float*)d_in[7];
    const float* bh  = (const float*)d_in[8];
    const float* Wc1 = (const float*)d_in[9];
    const float* bc1 = (const float*)d_in[10];
    const float* Wc2 = (const float*)d_in[11];
    const float* bc2 = (const float*)d_in[12];
    const int* src      = (const int*)d_in[13];
    const int* dst      = (const int*)d_in[14];
    const int* sidx     = (const int*)d_in[15];
    const int* lengths  = (const int*)d_in[16];
    float* out = (float*)d_out;

    char* ws = (char*)d_ws;
    size_t off = 0;
    auto alloc = [&](size_t bytes) -> void* {
        void* p = ws + off;
        off = (off + bytes + 255) & ~(size_t)255;
        return p;
    };
    float* agg      = (float*)alloc(sizeof(float) * (size_t)N_NODES * EMB);
    float* hbuf     = (float*)alloc(sizeof(float) * (size_t)N_NODES * EMB);
    __hip_bfloat16* hn_bf = (__hip_bfloat16*)alloc(2 * (size_t)N_NODES * EMB);
    int*   row_ptr  = (int*)alloc(sizeof(int) * (N_NODES + 1));
    int*   cnt      = (int*)alloc(sizeof(int) * N_NODES);
    int*   edge_src = (int*)alloc(sizeof(int) * N_EDGES);
    __hip_bfloat16* Wcat = (__hip_bfloat16*)alloc(2 * 1024 * 384);
    float* bsum     = (float*)alloc(sizeof(float) * 1024);
    __hip_bfloat16* hA = (__hip_bfloat16*)alloc(2 * NSENT * LH);
    __hip_bfloat16* hB = (__hip_bfloat16*)alloc(2 * NSENT * LH);
    float* cst      = (float*)alloc(sizeof(float) * NSENT * LH);
    float* hlast    = (float*)alloc(sizeof(float) * NSENT * LH);

    // CSR build
    hipMemsetAsync(cnt, 0, sizeof(int) * N_NODES, stream);
    k_hist<<<(N_EDGES + 255) / 256, 256, 0, stream>>>(dst, cnt);
    k_scan<<<1, 1024, 0, stream>>>(cnt, row_ptr);
    hipMemsetAsync(cnt, 0, sizeof(int) * N_NODES, stream);
    k_scatter<<<(N_EDGES + 255) / 256, 256, 0, stream>>>(src, dst, row_ptr, cnt, edge_src);

    // weight prep (bf16 pack) — independent of CSR, overlaps fine in-stream
    k_prep<<<(1024 * 384 + 1024 + 255) / 256, 256, 0, stream>>>(Wi, Wh, bi, bh, Wcat, bsum);

    // GCN
    k_aggregate<<<(N_NODES * 64) / 256, 256, 0, stream>>>(inputs, row_ptr, edge_src, agg);
    k_gcn_gemm<<<N_NODES / 16, 128, 0, stream>>>(agg, W1, b1, hbuf, 1);
    k_aggregate<<<(N_NODES * 64) / 256, 256, 0, stream>>>(hbuf, row_ptr, edge_src, agg);
    k_gcn_gemm_bf<<<N_NODES / 16, 128, 0, stream>>>(agg, W2, b2, hn_bf);

    // LSTM (bf16 MFMA)
    hipMemsetAsync(hA, 0, 2 * NSENT * LH, stream);
    hipMemsetAsync(cst, 0, sizeof(float) * NSENT * LH, stream);
    for (int t = 0; t < MAXLEN; t++) {
        __hip_bfloat16* hi = (t & 1) ? hB : hA;
        __hip_bfloat16* ho = (t & 1) ? hA : hB;
        k_lstm_mfma<<<dim3(NSENT / 32, 4), 256, 0, stream>>>(
            hn_bf, hi, Wcat, bsum, sidx, lengths, cst, ho, hlast, t);
    }

    // classifier
    k_classifier<<<NSENT / 4, 256, 0, stream>>>(hlast, Wc1, bc1, Wc2, bc2, out);
}